// Round 8
// baseline (236.359 us; speedup 1.0000x reference)
//
#include <hip/hip_runtime.h>
#include <hip/hip_bf16.h>
#include <stdint.h>

typedef __bf16 bf16x8 __attribute__((ext_vector_type(8)));
typedef float f32x4 __attribute__((ext_vector_type(4)));

#define T_SEQ 4096
#define C_DIM 1024
#define H_NUM 16
#define HD 64
#define C3 3072
#define NEG_BIG (-30000.0f)

__device__ __forceinline__ unsigned short f2bf(float f) {
    uint32_t u = __builtin_bit_cast(uint32_t, f);
    u += 0x7fffu + ((u >> 16) & 1u);
    return (unsigned short)(u >> 16);
}

__device__ __forceinline__ uint32_t pk_bf16(float a, float b) {
    __hip_bfloat162 h = __float22bfloat162_rn(float2{a, b});
    uint32_t u;
    __builtin_memcpy(&u, &h, sizeof(u));
    return u;
}

__device__ __forceinline__ bf16x8 ld_bf8(const unsigned short* p) {
    return *reinterpret_cast<const bf16x8*>(p);
}

__device__ __forceinline__ void async_g2l16(const unsigned short* g, unsigned short* l) {
    __builtin_amdgcn_global_load_lds(
        (const __attribute__((address_space(1))) void*)g,
        (__attribute__((address_space(3))) void*)l, 16, 0, 0);
}

__device__ __forceinline__ void store_c(unsigned short* C, size_t idx, float v) { C[idx] = f2bf(v); }
__device__ __forceinline__ void store_c(float* C, size_t idx, float v)          { C[idx] = v; }

__device__ __forceinline__ void cvt8(const float* src, unsigned short* dst) {
    float4 f0 = *(const float4*)src;
    float4 f1 = *(const float4*)(src + 4);
    union { uint32_t w[4]; uint4 q; } t;
    t.w[0] = pk_bf16(f0.x, f0.y);
    t.w[1] = pk_bf16(f0.z, f0.w);
    t.w[2] = pk_bf16(f1.x, f1.y);
    t.w[3] = pk_bf16(f1.z, f1.w);
    *(uint4*)dst = t.q;
}

// x, w_attn, (optionally w_proj) fp32 -> bf16 in one launch (concatenated index space)
__global__ void cvt_all(const float* __restrict__ x, const float* __restrict__ wa,
                        const float* __restrict__ wp,
                        unsigned short* __restrict__ xb, unsigned short* __restrict__ wab,
                        unsigned short* __restrict__ wpb) {
    int i = (blockIdx.x * blockDim.x + threadIdx.x) * 8;
    if (i < T_SEQ * C_DIM) { cvt8(x + i, xb + i); return; }
    i -= T_SEQ * C_DIM;
    if (i < C3 * C_DIM) { cvt8(wa + i, wab + i); return; }
    i -= C3 * C_DIM;
    if (wpb != nullptr && i < C_DIM * C_DIM) cvt8(wp + i, wpb + i);
}

__global__ void cvt_f32_bf16(const float* __restrict__ src, unsigned short* __restrict__ dst, int n) {
    int i = (blockIdx.x * blockDim.x + threadIdx.x) * 8;
    if (i >= n) return;
    cvt8(src + i, dst + i);
}

// C = A @ B^T, bf16, m97 async staging. Tile BM x 128, BK=32.
// If VT != nullptr, blocks with n0 >= 2048 (the V columns of qkv) write their
// output TRANSPOSED into VT[1024][4096] instead of C (fuses v_transpose).
template <int BM, typename TC>
__global__ __launch_bounds__(BM * 2, (BM == 128) ? 2 : 3) void gemm_bt(
    const unsigned short* __restrict__ A, const unsigned short* __restrict__ B,
    TC* __restrict__ C, unsigned short* __restrict__ VT, int M, int N, int K)
{
    __shared__ __attribute__((aligned(16))) unsigned short As[BM * 32];
    __shared__ __attribute__((aligned(16))) unsigned short Bs[128 * 32];

    const int tid  = threadIdx.x;
    const int wave = tid >> 6, lane = tid & 63;
    const int quad = lane >> 4, l16 = lane & 15;
    const int wm = (BM == 128) ? (wave >> 1) : 0;
    const int wn = (BM == 128) ? (wave & 1) : wave;
    const int m0 = blockIdx.y * BM, n0 = blockIdx.x * 128;

    const int sr   = lane >> 2;        // 0..15
    const int scol = (lane & 3) * 8;

    f32x4 acc[4][4] = {};

    for (int k0 = 0; k0 < K; k0 += 32) {
        if constexpr (BM == 128) {
            const unsigned short* ga = A + (size_t)(m0 + wave * 32 + sr) * K + k0 + scol;
            const unsigned short* gb = B + (size_t)(n0 + wave * 32 + sr) * K + k0 + scol;
            unsigned short* la = As + (wave * 32) * 32;
            unsigned short* lb = Bs + (wave * 32) * 32;
            async_g2l16(ga, la);
            async_g2l16(ga + (size_t)16 * K, la + 16 * 32);
            async_g2l16(gb, lb);
            async_g2l16(gb + (size_t)16 * K, lb + 16 * 32);
        } else {
            const unsigned short* ga = A + (size_t)(m0 + wave * 32 + sr) * K + k0 + scol;
            unsigned short* la = As + (wave * 32) * 32;
            async_g2l16(ga, la);
            async_g2l16(ga + (size_t)16 * K, la + 16 * 32);
            const unsigned short* gb = B + (size_t)(n0 + wave * 64 + sr) * K + k0 + scol;
            unsigned short* lb = Bs + (wave * 64) * 32;
            async_g2l16(gb, lb);
            async_g2l16(gb + (size_t)16 * K, lb + 16 * 32);
            async_g2l16(gb + (size_t)32 * K, lb + 32 * 32);
            async_g2l16(gb + (size_t)48 * K, lb + 48 * 32);
        }
        __syncthreads();

        bf16x8 af[4], bf[4];
        #pragma unroll
        for (int i = 0; i < 4; ++i) {
            af[i] = ld_bf8(As + (wm * 64 + i * 16 + l16) * 32 + quad * 8);
            bf[i] = ld_bf8(Bs + (wn * 64 + i * 16 + l16) * 32 + quad * 8);
        }
        #pragma unroll
        for (int mt = 0; mt < 4; ++mt)
            #pragma unroll
            for (int nt = 0; nt < 4; ++nt)
                acc[mt][nt] = __builtin_amdgcn_mfma_f32_16x16x32_bf16(
                    af[mt], bf[nt], acc[mt][nt], 0, 0, 0);
        __syncthreads();
    }

    if (VT != nullptr && n0 >= 2 * C_DIM) {
        #pragma unroll
        for (int mt = 0; mt < 4; ++mt)
            #pragma unroll
            for (int nt = 0; nt < 4; ++nt) {
                const int ch = n0 - 2 * C_DIM + wn * 64 + nt * 16 + l16;
                const int t0 = m0 + wm * 64 + mt * 16 + quad * 4;
                union { unsigned short u[4]; uint2 q; } pk;
                #pragma unroll
                for (int r = 0; r < 4; ++r) pk.u[r] = f2bf(acc[mt][nt][r]);
                *(uint2*)(VT + (size_t)ch * T_SEQ + t0) = pk.q;
            }
    } else {
        #pragma unroll
        for (int mt = 0; mt < 4; ++mt)
            #pragma unroll
            for (int nt = 0; nt < 4; ++nt)
                #pragma unroll
                for (int r = 0; r < 4; ++r) {
                    int row = m0 + wm * 64 + mt * 16 + quad * 4 + r;
                    int col = n0 + wn * 64 + nt * 16 + l16;
                    store_c(C, (size_t)row * N + col, acc[mt][nt][r]);
                }
    }
}

// Register-level quad transpose for the P fragment (replaces the LDS round-trip).
#if __has_builtin(__builtin_amdgcn_permlane32_swap) && __has_builtin(__builtin_amdgcn_permlane16_swap)
#define HAVE_PERMLANE_SWAP 1
#else
#define HAVE_PERMLANE_SWAP 0
#endif

__device__ __forceinline__ void quad_xpose_pair(uint32_t X, uint32_t Y,
                                                uint32_t& t0, uint32_t& t1) {
#if HAVE_PERMLANE_SWAP
    auto S = __builtin_amdgcn_permlane32_swap((int)X, (int)Y, false, false);
    auto T = __builtin_amdgcn_permlane16_swap((int)S[0], (int)S[1], false, false);
    t0 = (uint32_t)T[0];
    t1 = (uint32_t)T[1];
#else
    const unsigned l = threadIdx.x & 63;
    uint32_t Ys = (uint32_t)__shfl_xor((int)Y, 32, 64);
    uint32_t Xs = (uint32_t)__shfl_xor((int)X, 32, 64);
    uint32_t S0 = (l < 32) ? X : Ys;   // {A.low32, B.low32}
    uint32_t S1 = (l < 32) ? Xs : Y;   // {A.high32, B.high32}
    uint32_t S0s = (uint32_t)__shfl_xor((int)S0, 16, 64);
    uint32_t S1s = (uint32_t)__shfl_xor((int)S1, 16, 64);
    t0 = (l & 16) ? S1s : S0;
    t1 = (l & 16) ? S1 : S0s;
#endif
}

// One flash tile, 32 q-rows/wave (2 q-subtiles), max-free softmax.
// P stays in registers: quad-permutation via permlane swaps, no LDS round-trip.
template <bool MASK>
__device__ __forceinline__ void fa7_tile(
    const unsigned short* Ksb, const unsigned short* Vsb,
    const bf16x8 qf[2][2], f32x4 o[2][4], float* l_part,
    int k0, int q_abs0, int quad, int l16, int fo0, int fo1)
{
    const unsigned short* krow = Ksb + l16 * 64;
    bf16x8 kf[4][2];
    #pragma unroll
    for (int s = 0; s < 4; ++s) {
        kf[s][0] = ld_bf8(krow + s * 1024 + fo0);
        kf[s][1] = ld_bf8(krow + s * 1024 + fo1);
    }

    bf16x8 pf[2][2];
    #pragma unroll
    for (int qs = 0; qs < 2; ++qs) {
        f32x4 st[4];
        __builtin_amdgcn_s_setprio(1);
        #pragma unroll
        for (int s = 0; s < 4; ++s) {
            f32x4 z = {};
            z = __builtin_amdgcn_mfma_f32_16x16x32_bf16(kf[s][0], qf[qs][0], z, 0, 0, 0);
            st[s] = __builtin_amdgcn_mfma_f32_16x16x32_bf16(kf[s][1], qf[qs][1], z, 0, 0, 0);
        }
        __builtin_amdgcn_s_setprio(0);

        float ts = 0.f;
        #pragma unroll
        for (int s = 0; s < 4; ++s)
            #pragma unroll
            for (int r = 0; r < 4; ++r) {
                float v = st[s][r];
                if (MASK) {
                    int key = k0 + s * 16 + quad * 4 + r;
                    v = (key <= q_abs0 + qs * 16) ? v : NEG_BIG;
                }
                float e = __builtin_amdgcn_exp2f(v);   // exp2(-30000) = 0
                st[s][r] = e;
                ts += e;
            }
        l_part[qs] += ts;

        // pack P to bf16 pairs: W[s][p] = keys 16s+4*quad+2p..+1 (col = l16)
        uint32_t W[4][2];
        #pragma unroll
        for (int s = 0; s < 4; ++s) {
            W[s][0] = pk_bf16(st[s][0], st[s][1]);
            W[s][1] = pk_bf16(st[s][2], st[s][3]);
        }
        // redistribute across quads so lane holds keys 8*quad..8*quad+7 (B-operand)
        union { uint32_t w[4]; bf16x8 v; } pA, pB;
        quad_xpose_pair(W[0][0], W[1][0], pA.w[0], pA.w[2]);
        quad_xpose_pair(W[0][1], W[1][1], pA.w[1], pA.w[3]);
        quad_xpose_pair(W[2][0], W[3][0], pB.w[0], pB.w[2]);
        quad_xpose_pair(W[2][1], W[3][1], pB.w[1], pB.w[3]);
        pf[qs][0] = pA.v;   // keys  0..31
        pf[qs][1] = pB.v;   // keys 32..63
    }

    const unsigned short* vrow = Vsb + l16 * 64;
    bf16x8 vf[4][2];
    #pragma unroll
    for (int c = 0; c < 4; ++c) {
        vf[c][0] = ld_bf8(vrow + c * 1024 + fo0);
        vf[c][1] = ld_bf8(vrow + c * 1024 + fo1);
    }
    __builtin_amdgcn_s_setprio(1);
    #pragma unroll
    for (int qs = 0; qs < 2; ++qs)
        #pragma unroll
        for (int c = 0; c < 4; ++c) {
            o[qs][c] = __builtin_amdgcn_mfma_f32_16x16x32_bf16(vf[c][0], pf[qs][0], o[qs][c], 0, 0, 0);
            o[qs][c] = __builtin_amdgcn_mfma_f32_16x16x32_bf16(vf[c][1], pf[qs][1], o[qs][c], 0, 0, 0);
        }
    __builtin_amdgcn_s_setprio(0);
}

// Flash v11: flash8 template, reshaped 8-wave blocks (wq x wk = 4x2), 128 q-rows.
// Same K/V pair-tile per round SHARED by 4 wq-groups -> same 64KB LDS but
// 16 waves/CU (4/SIMD). Same 1-barrier dbuf sync structure (proven R3/R5/R7).
__global__ __launch_bounds__(512, 4) void flash_attn11(
    const unsigned short* __restrict__ qkv,
    const unsigned short* __restrict__ Vt,
    unsigned short* __restrict__ Y)
{
    __shared__ __attribute__((aligned(16))) unsigned short Ks[2][2][4096]; // [buf][tile][64x64]
    __shared__ __attribute__((aligned(16))) unsigned short Vs[2][2][4096];

    const int tid  = threadIdx.x;
    const int wave = tid >> 6, lane = tid & 63;
    const int quad = lane >> 4, l16 = lane & 15;
    const int wq = wave >> 1, wk = wave & 1;

    // 512 blocks: gen-paired snake -> CU gets (j, 31-j): constant rounds/CU.
    const int bi  = blockIdx.x;
    const int gen = bi >> 8, s = bi & 255;
    const int h   = s & 15;
    const int idx = s >> 4;                    // 0..15
    const int j   = (gen == 0) ? (31 - idx) : idx;

    const int q0w    = j * 128 + wq * 32;
    const int q_abs0 = q0w + l16;              // qs=0 row; qs=1 adds 16
    const int sw  = l16 & 7;
    const int fo0 = (quad ^ sw) * 8;
    const int fo1 = ((quad + 4) ^ sw) * 8;

    // Q fragments (B-operand), prescaled by 0.125*log2(e); 2 q-subtiles
    bf16x8 qf[2][2];
    {
        const float QS = 0.125f * 1.44269504f;
        #pragma unroll
        for (int qs = 0; qs < 2; ++qs) {
            const unsigned short* qp =
                qkv + (size_t)(q0w + qs * 16 + l16) * C3 + h * HD + quad * 8;
            bf16x8 a = ld_bf8(qp), b = ld_bf8(qp + 32);
            #pragma unroll
            for (int i = 0; i < 8; ++i) {
                qf[qs][0][i] = (__bf16)((float)a[i] * QS);
                qf[qs][1][i] = (__bf16)((float)b[i] * QS);
            }
        }
    }

    // Staging roles: wave w -> tile tt = w>>1 (K0,K1,V0,V1), half hf = w&1.
    // 4 g2l16 calls/wave/round (32 rows of the tile-half).
    const int tt = wave >> 1, hf = wave & 1;
    const int srow   = lane >> 3;              // 0..7
    const int schunk = (lane & 7) ^ srow;      // XOR swizzle chunk (row&7 == srow)
    const unsigned short* gp;
    size_t gstep, rstep;
    unsigned short* lbase;
    if (tt < 2) {
        gp = qkv + (size_t)(tt * 64 + hf * 32 + srow) * C3 + C_DIM + h * HD + schunk * 8;
        gstep = (size_t)8 * C3;
        rstep = (size_t)128 * C3;
        lbase = &Ks[0][tt][(hf * 32) * 64];
    } else {
        const int vt = tt - 2;
        gp = Vt + (size_t)(h * HD + hf * 32 + srow) * T_SEQ + vt * 64 + schunk * 8;
        gstep = (size_t)8 * T_SEQ;
        rstep = (size_t)128;
        lbase = &Vs[0][vt][(hf * 32) * 64];
    }
    const int lds_db = 2 * 4096;               // shorts between buf0/buf1 same tile

    auto stage = [&](int b) {
        #pragma unroll
        for (int jj = 0; jj < 4; ++jj)
            async_g2l16(gp + jj * gstep, lbase + b * lds_db + jj * 8 * 64);
    };

    f32x4 o[2][4] = {};
    float l_part[2] = {0.f, 0.f};

    const int nt = 2 * (j + 1);
    const int R  = j + 1;
    stage(0);
    gp += rstep;

    for (int r = 0; r < R; ++r) {
        __syncthreads();
        const int b = r & 1;
        if (r + 1 < R) {
            stage(1 - b);
            gp += rstep;
        }
        const int t = 2 * r + wk;
        if (t < nt && t * 64 <= q0w + 31) {
            if (t * 64 + 63 <= q0w)
                fa7_tile<false>(&Ks[b][wk][0], &Vs[b][wk][0], qf, o, l_part,
                                t * 64, q_abs0, quad, l16, fo0, fo1);
            else
                fa7_tile<true>(&Ks[b][wk][0], &Vs[b][wk][0], qf, o, l_part,
                               t * 64, q_abs0, quad, l16, fo0, fo1);
        }
    }

    // Cross-wk reduction through LDS (max-free softmax: partials just add).
    __syncthreads();
    float* red  = (float*)&Ks[0][0][0];        // 32 KB (all of Ks)
    float* lred = (float*)&Vs[0][0][0];        // 2 KB used
    if (wk == 1) {
        #pragma unroll
        for (int qs = 0; qs < 2; ++qs)
            #pragma unroll
            for (int c = 0; c < 4; ++c)
                *(f32x4*)&red[((wq * 8 + qs * 4 + c) * 64 + lane) * 4] = o[qs][c];
        lred[wq * 128 + lane * 2 + 0] = l_part[0];
        lred[wq * 128 + lane * 2 + 1] = l_part[1];
    }
    __syncthreads();
    if (wk == 0) {
        #pragma unroll
        for (int qs = 0; qs < 2; ++qs) {
            #pragma unroll
            for (int c = 0; c < 4; ++c) {
                f32x4 p = *(f32x4*)&red[((wq * 8 + qs * 4 + c) * 64 + lane) * 4];
                o[qs][c] += p;
            }
            l_part[qs] += lred[wq * 128 + lane * 2 + qs];
        }

        #pragma unroll
        for (int qs = 0; qs < 2; ++qs) {
            float l = l_part[qs];
            l += __shfl_xor(l, 16, 64);
            l += __shfl_xor(l, 32, 64);
            float inv_l = 1.f / l;
            #pragma unroll
            for (int c = 0; c < 4; ++c) {
                union { uint32_t w[2]; uint2 q; } t;
                t.w[0] = pk_bf16(o[qs][c][0] * inv_l, o[qs][c][1] * inv_l);
                t.w[1] = pk_bf16(o[qs][c][2] * inv_l, o[qs][c][3] * inv_l);
                *(uint2*)(Y + (size_t)(q_abs0 + qs * 16) * C_DIM + h * HD + c * 16 + quad * 4) = t.q;
            }
        }
    }
}

extern "C" void kernel_launch(void* const* d_in, const int* in_sizes, int n_in,
                              void* d_out, int out_size, void* d_ws, size_t ws_size,
                              hipStream_t stream) {
    const float* x      = (const float*)d_in[0];
    const float* w_attn = (const float*)d_in[1];
    const float* w_proj = (const float*)d_in[2];
    float* out = (float*)d_out;

    unsigned short* qkv = (unsigned short*)d_ws;            // [4096,3072] bf16 (V cols unused)
    unsigned short* xb  = qkv + (size_t)T_SEQ * C3;         // [4096,1024] bf16
    unsigned short* y   = xb;                               // alias after gemm1
    unsigned short* Vt  = (unsigned short*)d_out;           // [1024][4096] bf16
    unsigned short* wab = Vt + (size_t)C_DIM * T_SEQ;       // [3072,1024] bf16

    const size_t need = ((size_t)T_SEQ * C3 + (size_t)T_SEQ * C_DIM +
                         (size_t)C_DIM * C_DIM) * sizeof(unsigned short);
    const bool fuse_wp = ws_size >= need;
    unsigned short* wpb = fuse_wp ? (xb + (size_t)T_SEQ * C_DIM)
                                  : qkv;

    if (fuse_wp) {
        const int n8 = (T_SEQ * C_DIM + C3 * C_DIM + C_DIM * C_DIM) / 8;
        cvt_all<<<n8 / 256, 256, 0, stream>>>(x, w_attn, w_proj, xb, wab, wpb);
    } else {
        const int n8 = (T_SEQ * C_DIM + C3 * C_DIM) / 8;
        cvt_all<<<n8 / 256, 256, 0, stream>>>(x, w_attn, nullptr, xb, wab, nullptr);
    }

    // gemm1 with fused V-transpose epilogue (V blocks write Vt directly)
    gemm_bt<128, unsigned short>
        <<<dim3(C3 / 128, T_SEQ / 128), 256, 0, stream>>>(xb, wab, qkv, Vt, T_SEQ, C3, C_DIM);

    flash_attn11<<<dim3(512), 512, 0, stream>>>(qkv, Vt, y);

    if (!fuse_wp) {
        cvt_f32_bf16<<<(C_DIM * C_DIM / 8 + 255) / 256, 256, 0, stream>>>(w_proj, wpb, C_DIM * C_DIM);
    }

    gemm_bt<64, float>
        <<<dim3(C_DIM / 128, T_SEQ / 64), 128, 0, stream>>>(y, wpb, out, nullptr, T_SEQ, C_DIM, C_DIM);
}

// Round 9
// 202.992 us; speedup vs baseline: 1.1644x; 1.1644x over previous
//
#include <hip/hip_runtime.h>
#include <hip/hip_bf16.h>
#include <stdint.h>

typedef __bf16 bf16x8 __attribute__((ext_vector_type(8)));
typedef float f32x4 __attribute__((ext_vector_type(4)));

#define T_SEQ 4096
#define C_DIM 1024
#define H_NUM 16
#define HD 64
#define C3 3072
#define NEG_BIG (-30000.0f)

__device__ __forceinline__ unsigned short f2bf(float f) {
    uint32_t u = __builtin_bit_cast(uint32_t, f);
    u += 0x7fffu + ((u >> 16) & 1u);
    return (unsigned short)(u >> 16);
}

__device__ __forceinline__ uint32_t pk_bf16(float a, float b) {
    __hip_bfloat162 h = __float22bfloat162_rn(float2{a, b});
    uint32_t u;
    __builtin_memcpy(&u, &h, sizeof(u));
    return u;
}

__device__ __forceinline__ bf16x8 ld_bf8(const unsigned short* p) {
    return *reinterpret_cast<const bf16x8*>(p);
}

__device__ __forceinline__ void async_g2l16(const unsigned short* g, unsigned short* l) {
    __builtin_amdgcn_global_load_lds(
        (const __attribute__((address_space(1))) void*)g,
        (__attribute__((address_space(3))) void*)l, 16, 0, 0);
}

__device__ __forceinline__ void store_c(unsigned short* C, size_t idx, float v) { C[idx] = f2bf(v); }
__device__ __forceinline__ void store_c(float* C, size_t idx, float v)          { C[idx] = v; }

__device__ __forceinline__ void cvt8(const float* src, unsigned short* dst) {
    float4 f0 = *(const float4*)src;
    float4 f1 = *(const float4*)(src + 4);
    union { uint32_t w[4]; uint4 q; } t;
    t.w[0] = pk_bf16(f0.x, f0.y);
    t.w[1] = pk_bf16(f0.z, f0.w);
    t.w[2] = pk_bf16(f1.x, f1.y);
    t.w[3] = pk_bf16(f1.z, f1.w);
    *(uint4*)dst = t.q;
}

// x, w_attn, (optionally w_proj) fp32 -> bf16 in one launch (concatenated index space)
__global__ void cvt_all(const float* __restrict__ x, const float* __restrict__ wa,
                        const float* __restrict__ wp,
                        unsigned short* __restrict__ xb, unsigned short* __restrict__ wab,
                        unsigned short* __restrict__ wpb) {
    int i = (blockIdx.x * blockDim.x + threadIdx.x) * 8;
    if (i < T_SEQ * C_DIM) { cvt8(x + i, xb + i); return; }
    i -= T_SEQ * C_DIM;
    if (i < C3 * C_DIM) { cvt8(wa + i, wab + i); return; }
    i -= C3 * C_DIM;
    if (wpb != nullptr && i < C_DIM * C_DIM) cvt8(wp + i, wpb + i);
}

__global__ void cvt_f32_bf16(const float* __restrict__ src, unsigned short* __restrict__ dst, int n) {
    int i = (blockIdx.x * blockDim.x + threadIdx.x) * 8;
    if (i >= n) return;
    cvt8(src + i, dst + i);
}

// C = A @ B^T, bf16, m97 async staging. Tile BM x 128, BK=32.
// If VT != nullptr, blocks with n0 >= 2048 (the V columns of qkv) write their
// output TRANSPOSED into VT[1024][4096] instead of C (fuses v_transpose).
template <int BM, typename TC>
__global__ __launch_bounds__(BM * 2, (BM == 128) ? 2 : 3) void gemm_bt(
    const unsigned short* __restrict__ A, const unsigned short* __restrict__ B,
    TC* __restrict__ C, unsigned short* __restrict__ VT, int M, int N, int K)
{
    __shared__ __attribute__((aligned(16))) unsigned short As[BM * 32];
    __shared__ __attribute__((aligned(16))) unsigned short Bs[128 * 32];

    const int tid  = threadIdx.x;
    const int wave = tid >> 6, lane = tid & 63;
    const int quad = lane >> 4, l16 = lane & 15;
    const int wm = (BM == 128) ? (wave >> 1) : 0;
    const int wn = (BM == 128) ? (wave & 1) : wave;
    const int m0 = blockIdx.y * BM, n0 = blockIdx.x * 128;

    const int sr   = lane >> 2;        // 0..15
    const int scol = (lane & 3) * 8;

    f32x4 acc[4][4] = {};

    for (int k0 = 0; k0 < K; k0 += 32) {
        if constexpr (BM == 128) {
            const unsigned short* ga = A + (size_t)(m0 + wave * 32 + sr) * K + k0 + scol;
            const unsigned short* gb = B + (size_t)(n0 + wave * 32 + sr) * K + k0 + scol;
            unsigned short* la = As + (wave * 32) * 32;
            unsigned short* lb = Bs + (wave * 32) * 32;
            async_g2l16(ga, la);
            async_g2l16(ga + (size_t)16 * K, la + 16 * 32);
            async_g2l16(gb, lb);
            async_g2l16(gb + (size_t)16 * K, lb + 16 * 32);
        } else {
            const unsigned short* ga = A + (size_t)(m0 + wave * 32 + sr) * K + k0 + scol;
            unsigned short* la = As + (wave * 32) * 32;
            async_g2l16(ga, la);
            async_g2l16(ga + (size_t)16 * K, la + 16 * 32);
            const unsigned short* gb = B + (size_t)(n0 + wave * 64 + sr) * K + k0 + scol;
            unsigned short* lb = Bs + (wave * 64) * 32;
            async_g2l16(gb, lb);
            async_g2l16(gb + (size_t)16 * K, lb + 16 * 32);
            async_g2l16(gb + (size_t)32 * K, lb + 32 * 32);
            async_g2l16(gb + (size_t)48 * K, lb + 48 * 32);
        }
        __syncthreads();

        bf16x8 af[4], bf[4];
        #pragma unroll
        for (int i = 0; i < 4; ++i) {
            af[i] = ld_bf8(As + (wm * 64 + i * 16 + l16) * 32 + quad * 8);
            bf[i] = ld_bf8(Bs + (wn * 64 + i * 16 + l16) * 32 + quad * 8);
        }
        #pragma unroll
        for (int mt = 0; mt < 4; ++mt)
            #pragma unroll
            for (int nt = 0; nt < 4; ++nt)
                acc[mt][nt] = __builtin_amdgcn_mfma_f32_16x16x32_bf16(
                    af[mt], bf[nt], acc[mt][nt], 0, 0, 0);
        __syncthreads();
    }

    if (VT != nullptr && n0 >= 2 * C_DIM) {
        #pragma unroll
        for (int mt = 0; mt < 4; ++mt)
            #pragma unroll
            for (int nt = 0; nt < 4; ++nt) {
                const int ch = n0 - 2 * C_DIM + wn * 64 + nt * 16 + l16;
                const int t0 = m0 + wm * 64 + mt * 16 + quad * 4;
                union { unsigned short u[4]; uint2 q; } pk;
                #pragma unroll
                for (int r = 0; r < 4; ++r) pk.u[r] = f2bf(acc[mt][nt][r]);
                *(uint2*)(VT + (size_t)ch * T_SEQ + t0) = pk.q;
            }
    } else {
        #pragma unroll
        for (int mt = 0; mt < 4; ++mt)
            #pragma unroll
            for (int nt = 0; nt < 4; ++nt)
                #pragma unroll
                for (int r = 0; r < 4; ++r) {
                    int row = m0 + wm * 64 + mt * 16 + quad * 4 + r;
                    int col = n0 + wn * 64 + nt * 16 + l16;
                    store_c(C, (size_t)row * N + col, acc[mt][nt][r]);
                }
    }
}

// Register-level quad transpose for the P fragment (replaces the LDS round-trip).
#if __has_builtin(__builtin_amdgcn_permlane32_swap) && __has_builtin(__builtin_amdgcn_permlane16_swap)
#define HAVE_PERMLANE_SWAP 1
#else
#define HAVE_PERMLANE_SWAP 0
#endif

__device__ __forceinline__ void quad_xpose_pair(uint32_t X, uint32_t Y,
                                                uint32_t& t0, uint32_t& t1) {
#if HAVE_PERMLANE_SWAP
    auto S = __builtin_amdgcn_permlane32_swap((int)X, (int)Y, false, false);
    auto T = __builtin_amdgcn_permlane16_swap((int)S[0], (int)S[1], false, false);
    t0 = (uint32_t)T[0];
    t1 = (uint32_t)T[1];
#else
    const unsigned l = threadIdx.x & 63;
    uint32_t Ys = (uint32_t)__shfl_xor((int)Y, 32, 64);
    uint32_t Xs = (uint32_t)__shfl_xor((int)X, 32, 64);
    uint32_t S0 = (l < 32) ? X : Ys;   // {A.low32, B.low32}
    uint32_t S1 = (l < 32) ? Xs : Y;   // {A.high32, B.high32}
    uint32_t S0s = (uint32_t)__shfl_xor((int)S0, 16, 64);
    uint32_t S1s = (uint32_t)__shfl_xor((int)S1, 16, 64);
    t0 = (l & 16) ? S1s : S0;
    t1 = (l & 16) ? S1 : S0s;
#endif
}

// One flash tile, 32 q-rows/wave (2 q-subtiles), max-free softmax.
// P stays in registers: quad-permutation via permlane swaps, no LDS round-trip.
template <bool MASK>
__device__ __forceinline__ void fa7_tile(
    const unsigned short* Ksb, const unsigned short* Vsb,
    const bf16x8 qf[2][2], f32x4 o[2][4], float* l_part,
    int k0, int q_abs0, int quad, int l16, int fo0, int fo1)
{
    const unsigned short* krow = Ksb + l16 * 64;
    bf16x8 kf[4][2];
    #pragma unroll
    for (int s = 0; s < 4; ++s) {
        kf[s][0] = ld_bf8(krow + s * 1024 + fo0);
        kf[s][1] = ld_bf8(krow + s * 1024 + fo1);
    }

    bf16x8 pf[2][2];
    #pragma unroll
    for (int qs = 0; qs < 2; ++qs) {
        f32x4 st[4];
        __builtin_amdgcn_s_setprio(1);
        #pragma unroll
        for (int s = 0; s < 4; ++s) {
            f32x4 z = {};
            z = __builtin_amdgcn_mfma_f32_16x16x32_bf16(kf[s][0], qf[qs][0], z, 0, 0, 0);
            st[s] = __builtin_amdgcn_mfma_f32_16x16x32_bf16(kf[s][1], qf[qs][1], z, 0, 0, 0);
        }
        __builtin_amdgcn_s_setprio(0);

        float ts = 0.f;
        #pragma unroll
        for (int s = 0; s < 4; ++s)
            #pragma unroll
            for (int r = 0; r < 4; ++r) {
                float v = st[s][r];
                if (MASK) {
                    int key = k0 + s * 16 + quad * 4 + r;
                    v = (key <= q_abs0 + qs * 16) ? v : NEG_BIG;
                }
                float e = __builtin_amdgcn_exp2f(v);   // exp2(-30000) = 0
                st[s][r] = e;
                ts += e;
            }
        l_part[qs] += ts;

        // pack P to bf16 pairs: W[s][p] = keys 16s+4*quad+2p..+1 (col = l16)
        uint32_t W[4][2];
        #pragma unroll
        for (int s = 0; s < 4; ++s) {
            W[s][0] = pk_bf16(st[s][0], st[s][1]);
            W[s][1] = pk_bf16(st[s][2], st[s][3]);
        }
        // redistribute across quads so lane holds keys 8*quad..8*quad+7 (B-operand)
        union { uint32_t w[4]; bf16x8 v; } pA, pB;
        quad_xpose_pair(W[0][0], W[1][0], pA.w[0], pA.w[2]);
        quad_xpose_pair(W[0][1], W[1][1], pA.w[1], pA.w[3]);
        quad_xpose_pair(W[2][0], W[3][0], pB.w[0], pB.w[2]);
        quad_xpose_pair(W[2][1], W[3][1], pB.w[1], pB.w[3]);
        pf[qs][0] = pA.v;   // keys  0..31
        pf[qs][1] = pB.v;   // keys 32..63
    }

    const unsigned short* vrow = Vsb + l16 * 64;
    bf16x8 vf[4][2];
    #pragma unroll
    for (int c = 0; c < 4; ++c) {
        vf[c][0] = ld_bf8(vrow + c * 1024 + fo0);
        vf[c][1] = ld_bf8(vrow + c * 1024 + fo1);
    }
    __builtin_amdgcn_s_setprio(1);
    #pragma unroll
    for (int qs = 0; qs < 2; ++qs)
        #pragma unroll
        for (int c = 0; c < 4; ++c) {
            o[qs][c] = __builtin_amdgcn_mfma_f32_16x16x32_bf16(vf[c][0], pf[qs][0], o[qs][c], 0, 0, 0);
            o[qs][c] = __builtin_amdgcn_mfma_f32_16x16x32_bf16(vf[c][1], pf[qs][1], o[qs][c], 0, 0, 0);
        }
    __builtin_amdgcn_s_setprio(0);
}

// Flash v11b: 8-wave blocks (wq x wk = 4x2), 128 q-rows, K/V pair-tile shared
// by 4 wq-groups. 64KB LDS, 2 blocks/CU -> 16 waves/CU (4/SIMD).
// launch_bounds(512,2): VGPR cap >= 128 under either arg-2 semantics -> no
// spill (R8's (512,4) capped VGPR at 64 -> 133MB scratch traffic).
__global__ __launch_bounds__(512, 2) void flash_attn11(
    const unsigned short* __restrict__ qkv,
    const unsigned short* __restrict__ Vt,
    unsigned short* __restrict__ Y)
{
    __shared__ __attribute__((aligned(16))) unsigned short Ks[2][2][4096]; // [buf][tile][64x64]
    __shared__ __attribute__((aligned(16))) unsigned short Vs[2][2][4096];

    const int tid  = threadIdx.x;
    const int wave = tid >> 6, lane = tid & 63;
    const int quad = lane >> 4, l16 = lane & 15;
    const int wq = wave >> 1, wk = wave & 1;

    // 512 blocks: gen-paired snake -> CU gets (j, 31-j): constant rounds/CU.
    const int bi  = blockIdx.x;
    const int gen = bi >> 8, s = bi & 255;
    const int h   = s & 15;
    const int idx = s >> 4;                    // 0..15
    const int j   = (gen == 0) ? (31 - idx) : idx;

    const int q0w    = j * 128 + wq * 32;
    const int q_abs0 = q0w + l16;              // qs=0 row; qs=1 adds 16
    const int sw  = l16 & 7;
    const int fo0 = (quad ^ sw) * 8;
    const int fo1 = ((quad + 4) ^ sw) * 8;

    // Q fragments (B-operand), prescaled by 0.125*log2(e); 2 q-subtiles
    bf16x8 qf[2][2];
    {
        const float QS = 0.125f * 1.44269504f;
        #pragma unroll
        for (int qs = 0; qs < 2; ++qs) {
            const unsigned short* qp =
                qkv + (size_t)(q0w + qs * 16 + l16) * C3 + h * HD + quad * 8;
            bf16x8 a = ld_bf8(qp), b = ld_bf8(qp + 32);
            #pragma unroll
            for (int i = 0; i < 8; ++i) {
                qf[qs][0][i] = (__bf16)((float)a[i] * QS);
                qf[qs][1][i] = (__bf16)((float)b[i] * QS);
            }
        }
    }

    // Staging roles: wave w -> tile tt = w>>1 (K0,K1,V0,V1), half hf = w&1.
    // 4 g2l16 calls/wave/round (32 rows of the tile-half).
    const int tt = wave >> 1, hf = wave & 1;
    const int srow   = lane >> 3;              // 0..7
    const int schunk = (lane & 7) ^ srow;      // XOR swizzle chunk (row&7 == srow)
    const unsigned short* gp;
    size_t gstep, rstep;
    unsigned short* lbase;
    if (tt < 2) {
        gp = qkv + (size_t)(tt * 64 + hf * 32 + srow) * C3 + C_DIM + h * HD + schunk * 8;
        gstep = (size_t)8 * C3;
        rstep = (size_t)128 * C3;
        lbase = &Ks[0][tt][(hf * 32) * 64];
    } else {
        const int vt = tt - 2;
        gp = Vt + (size_t)(h * HD + hf * 32 + srow) * T_SEQ + vt * 64 + schunk * 8;
        gstep = (size_t)8 * T_SEQ;
        rstep = (size_t)128;
        lbase = &Vs[0][vt][(hf * 32) * 64];
    }
    const int lds_db = 2 * 4096;               // shorts between buf0/buf1 same tile

    auto stage = [&](int b) {
        #pragma unroll
        for (int jj = 0; jj < 4; ++jj)
            async_g2l16(gp + jj * gstep, lbase + b * lds_db + jj * 8 * 64);
    };

    f32x4 o[2][4] = {};
    float l_part[2] = {0.f, 0.f};

    const int nt = 2 * (j + 1);
    const int R  = j + 1;
    stage(0);
    gp += rstep;

    for (int r = 0; r < R; ++r) {
        __syncthreads();
        const int b = r & 1;
        if (r + 1 < R) {
            stage(1 - b);
            gp += rstep;
        }
        const int t = 2 * r + wk;
        if (t < nt && t * 64 <= q0w + 31) {
            if (t * 64 + 63 <= q0w)
                fa7_tile<false>(&Ks[b][wk][0], &Vs[b][wk][0], qf, o, l_part,
                                t * 64, q_abs0, quad, l16, fo0, fo1);
            else
                fa7_tile<true>(&Ks[b][wk][0], &Vs[b][wk][0], qf, o, l_part,
                               t * 64, q_abs0, quad, l16, fo0, fo1);
        }
    }

    // Cross-wk reduction through LDS (max-free softmax: partials just add).
    __syncthreads();
    float* red  = (float*)&Ks[0][0][0];        // 32 KB (all of Ks)
    float* lred = (float*)&Vs[0][0][0];        // 2 KB used
    if (wk == 1) {
        #pragma unroll
        for (int qs = 0; qs < 2; ++qs)
            #pragma unroll
            for (int c = 0; c < 4; ++c)
                *(f32x4*)&red[((wq * 8 + qs * 4 + c) * 64 + lane) * 4] = o[qs][c];
        lred[wq * 128 + lane * 2 + 0] = l_part[0];
        lred[wq * 128 + lane * 2 + 1] = l_part[1];
    }
    __syncthreads();
    if (wk == 0) {
        #pragma unroll
        for (int qs = 0; qs < 2; ++qs) {
            #pragma unroll
            for (int c = 0; c < 4; ++c) {
                f32x4 p = *(f32x4*)&red[((wq * 8 + qs * 4 + c) * 64 + lane) * 4];
                o[qs][c] += p;
            }
            l_part[qs] += lred[wq * 128 + lane * 2 + qs];
        }

        #pragma unroll
        for (int qs = 0; qs < 2; ++qs) {
            float l = l_part[qs];
            l += __shfl_xor(l, 16, 64);
            l += __shfl_xor(l, 32, 64);
            float inv_l = 1.f / l;
            #pragma unroll
            for (int c = 0; c < 4; ++c) {
                union { uint32_t w[2]; uint2 q; } t;
                t.w[0] = pk_bf16(o[qs][c][0] * inv_l, o[qs][c][1] * inv_l);
                t.w[1] = pk_bf16(o[qs][c][2] * inv_l, o[qs][c][3] * inv_l);
                *(uint2*)(Y + (size_t)(q_abs0 + qs * 16) * C_DIM + h * HD + c * 16 + quad * 4) = t.q;
            }
        }
    }
}

extern "C" void kernel_launch(void* const* d_in, const int* in_sizes, int n_in,
                              void* d_out, int out_size, void* d_ws, size_t ws_size,
                              hipStream_t stream) {
    const float* x      = (const float*)d_in[0];
    const float* w_attn = (const float*)d_in[1];
    const float* w_proj = (const float*)d_in[2];
    float* out = (float*)d_out;

    unsigned short* qkv = (unsigned short*)d_ws;            // [4096,3072] bf16 (V cols unused)
    unsigned short* xb  = qkv + (size_t)T_SEQ * C3;         // [4096,1024] bf16
    unsigned short* y   = xb;                               // alias after gemm1
    unsigned short* Vt  = (unsigned short*)d_out;           // [1024][4096] bf16
    unsigned short* wab = Vt + (size_t)C_DIM * T_SEQ;       // [3072,1024] bf16

    const size_t need = ((size_t)T_SEQ * C3 + (size_t)T_SEQ * C_DIM +
                         (size_t)C_DIM * C_DIM) * sizeof(unsigned short);
    const bool fuse_wp = ws_size >= need;
    unsigned short* wpb = fuse_wp ? (xb + (size_t)T_SEQ * C_DIM)
                                  : qkv;

    if (fuse_wp) {
        const int n8 = (T_SEQ * C_DIM + C3 * C_DIM + C_DIM * C_DIM) / 8;
        cvt_all<<<n8 / 256, 256, 0, stream>>>(x, w_attn, w_proj, xb, wab, wpb);
    } else {
        const int n8 = (T_SEQ * C_DIM + C3 * C_DIM) / 8;
        cvt_all<<<n8 / 256, 256, 0, stream>>>(x, w_attn, nullptr, xb, wab, nullptr);
    }

    // gemm1 with fused V-transpose epilogue (V blocks write Vt directly)
    gemm_bt<128, unsigned short>
        <<<dim3(C3 / 128, T_SEQ / 128), 256, 0, stream>>>(xb, wab, qkv, Vt, T_SEQ, C3, C_DIM);

    flash_attn11<<<dim3(512), 512, 0, stream>>>(qkv, Vt, y);

    if (!fuse_wp) {
        cvt_f32_bf16<<<(C_DIM * C_DIM / 8 + 255) / 256, 256, 0, stream>>>(w_proj, wpb, C_DIM * C_DIM);
    }

    gemm_bt<64, float>
        <<<dim3(C_DIM / 128, T_SEQ / 64), 128, 0, stream>>>(y, wpb, out, nullptr, T_SEQ, C_DIM, C_DIM);
}

// Round 10
// 189.982 us; speedup vs baseline: 1.2441x; 1.0685x over previous
//
#include <hip/hip_runtime.h>
#include <hip/hip_bf16.h>
#include <stdint.h>

typedef __bf16 bf16x8 __attribute__((ext_vector_type(8)));
typedef float f32x4 __attribute__((ext_vector_type(4)));

#define T_SEQ 4096
#define C_DIM 1024
#define H_NUM 16
#define HD 64
#define C3 3072
#define NEG_BIG (-30000.0f)

__device__ __forceinline__ unsigned short f2bf(float f) {
    uint32_t u = __builtin_bit_cast(uint32_t, f);
    u += 0x7fffu + ((u >> 16) & 1u);
    return (unsigned short)(u >> 16);
}

__device__ __forceinline__ uint32_t pk_bf16(float a, float b) {
    __hip_bfloat162 h = __float22bfloat162_rn(float2{a, b});
    uint32_t u;
    __builtin_memcpy(&u, &h, sizeof(u));
    return u;
}

__device__ __forceinline__ bf16x8 ld_bf8(const unsigned short* p) {
    return *reinterpret_cast<const bf16x8*>(p);
}

__device__ __forceinline__ void async_g2l16(const unsigned short* g, unsigned short* l) {
    __builtin_amdgcn_global_load_lds(
        (const __attribute__((address_space(1))) void*)g,
        (__attribute__((address_space(3))) void*)l, 16, 0, 0);
}

__device__ __forceinline__ void store_c(unsigned short* C, size_t idx, float v) { C[idx] = f2bf(v); }
__device__ __forceinline__ void store_c(float* C, size_t idx, float v)          { C[idx] = v; }

__device__ __forceinline__ void cvt8(const float* src, unsigned short* dst) {
    float4 f0 = *(const float4*)src;
    float4 f1 = *(const float4*)(src + 4);
    union { uint32_t w[4]; uint4 q; } t;
    t.w[0] = pk_bf16(f0.x, f0.y);
    t.w[1] = pk_bf16(f0.z, f0.w);
    t.w[2] = pk_bf16(f1.x, f1.y);
    t.w[3] = pk_bf16(f1.z, f1.w);
    *(uint4*)dst = t.q;
}

// x, w_attn, (optionally w_proj) fp32 -> bf16 in one launch (concatenated index space)
__global__ void cvt_all(const float* __restrict__ x, const float* __restrict__ wa,
                        const float* __restrict__ wp,
                        unsigned short* __restrict__ xb, unsigned short* __restrict__ wab,
                        unsigned short* __restrict__ wpb) {
    int i = (blockIdx.x * blockDim.x + threadIdx.x) * 8;
    if (i < T_SEQ * C_DIM) { cvt8(x + i, xb + i); return; }
    i -= T_SEQ * C_DIM;
    if (i < C3 * C_DIM) { cvt8(wa + i, wab + i); return; }
    i -= C3 * C_DIM;
    if (wpb != nullptr && i < C_DIM * C_DIM) cvt8(wp + i, wpb + i);
}

__global__ void cvt_f32_bf16(const float* __restrict__ src, unsigned short* __restrict__ dst, int n) {
    int i = (blockIdx.x * blockDim.x + threadIdx.x) * 8;
    if (i >= n) return;
    cvt8(src + i, dst + i);
}

// C = A @ B^T, bf16, m97 async staging. Tile BM x 128, BK=32.
// If VT != nullptr, blocks with n0 >= 2048 (the V columns of qkv) write their
// output TRANSPOSED into VT[1024][4096] instead of C (fuses v_transpose).
template <int BM, typename TC>
__global__ __launch_bounds__(BM * 2, (BM == 128) ? 2 : 3) void gemm_bt(
    const unsigned short* __restrict__ A, const unsigned short* __restrict__ B,
    TC* __restrict__ C, unsigned short* __restrict__ VT, int M, int N, int K)
{
    __shared__ __attribute__((aligned(16))) unsigned short As[BM * 32];
    __shared__ __attribute__((aligned(16))) unsigned short Bs[128 * 32];

    const int tid  = threadIdx.x;
    const int wave = tid >> 6, lane = tid & 63;
    const int quad = lane >> 4, l16 = lane & 15;
    const int wm = (BM == 128) ? (wave >> 1) : 0;
    const int wn = (BM == 128) ? (wave & 1) : wave;
    const int m0 = blockIdx.y * BM, n0 = blockIdx.x * 128;

    const int sr   = lane >> 2;        // 0..15
    const int scol = (lane & 3) * 8;

    f32x4 acc[4][4] = {};

    for (int k0 = 0; k0 < K; k0 += 32) {
        if constexpr (BM == 128) {
            const unsigned short* ga = A + (size_t)(m0 + wave * 32 + sr) * K + k0 + scol;
            const unsigned short* gb = B + (size_t)(n0 + wave * 32 + sr) * K + k0 + scol;
            unsigned short* la = As + (wave * 32) * 32;
            unsigned short* lb = Bs + (wave * 32) * 32;
            async_g2l16(ga, la);
            async_g2l16(ga + (size_t)16 * K, la + 16 * 32);
            async_g2l16(gb, lb);
            async_g2l16(gb + (size_t)16 * K, lb + 16 * 32);
        } else {
            const unsigned short* ga = A + (size_t)(m0 + wave * 32 + sr) * K + k0 + scol;
            unsigned short* la = As + (wave * 32) * 32;
            async_g2l16(ga, la);
            async_g2l16(ga + (size_t)16 * K, la + 16 * 32);
            const unsigned short* gb = B + (size_t)(n0 + wave * 64 + sr) * K + k0 + scol;
            unsigned short* lb = Bs + (wave * 64) * 32;
            async_g2l16(gb, lb);
            async_g2l16(gb + (size_t)16 * K, lb + 16 * 32);
            async_g2l16(gb + (size_t)32 * K, lb + 32 * 32);
            async_g2l16(gb + (size_t)48 * K, lb + 48 * 32);
        }
        __syncthreads();

        bf16x8 af[4], bf[4];
        #pragma unroll
        for (int i = 0; i < 4; ++i) {
            af[i] = ld_bf8(As + (wm * 64 + i * 16 + l16) * 32 + quad * 8);
            bf[i] = ld_bf8(Bs + (wn * 64 + i * 16 + l16) * 32 + quad * 8);
        }
        #pragma unroll
        for (int mt = 0; mt < 4; ++mt)
            #pragma unroll
            for (int nt = 0; nt < 4; ++nt)
                acc[mt][nt] = __builtin_amdgcn_mfma_f32_16x16x32_bf16(
                    af[mt], bf[nt], acc[mt][nt], 0, 0, 0);
        __syncthreads();
    }

    if (VT != nullptr && n0 >= 2 * C_DIM) {
        #pragma unroll
        for (int mt = 0; mt < 4; ++mt)
            #pragma unroll
            for (int nt = 0; nt < 4; ++nt) {
                const int ch = n0 - 2 * C_DIM + wn * 64 + nt * 16 + l16;
                const int t0 = m0 + wm * 64 + mt * 16 + quad * 4;
                union { unsigned short u[4]; uint2 q; } pk;
                #pragma unroll
                for (int r = 0; r < 4; ++r) pk.u[r] = f2bf(acc[mt][nt][r]);
                *(uint2*)(VT + (size_t)ch * T_SEQ + t0) = pk.q;
            }
    } else {
        #pragma unroll
        for (int mt = 0; mt < 4; ++mt)
            #pragma unroll
            for (int nt = 0; nt < 4; ++nt)
                #pragma unroll
                for (int r = 0; r < 4; ++r) {
                    int row = m0 + wm * 64 + mt * 16 + quad * 4 + r;
                    int col = n0 + wn * 64 + nt * 16 + l16;
                    store_c(C, (size_t)row * N + col, acc[mt][nt][r]);
                }
    }
}

// Register-level quad transpose for the P fragment (replaces the LDS round-trip).
#if __has_builtin(__builtin_amdgcn_permlane32_swap) && __has_builtin(__builtin_amdgcn_permlane16_swap)
#define HAVE_PERMLANE_SWAP 1
#else
#define HAVE_PERMLANE_SWAP 0
#endif

__device__ __forceinline__ void quad_xpose_pair(uint32_t X, uint32_t Y,
                                                uint32_t& t0, uint32_t& t1) {
#if HAVE_PERMLANE_SWAP
    auto S = __builtin_amdgcn_permlane32_swap((int)X, (int)Y, false, false);
    auto T = __builtin_amdgcn_permlane16_swap((int)S[0], (int)S[1], false, false);
    t0 = (uint32_t)T[0];
    t1 = (uint32_t)T[1];
#else
    const unsigned l = threadIdx.x & 63;
    uint32_t Ys = (uint32_t)__shfl_xor((int)Y, 32, 64);
    uint32_t Xs = (uint32_t)__shfl_xor((int)X, 32, 64);
    uint32_t S0 = (l < 32) ? X : Ys;   // {A.low32, B.low32}
    uint32_t S1 = (l < 32) ? Xs : Y;   // {A.high32, B.high32}
    uint32_t S0s = (uint32_t)__shfl_xor((int)S0, 16, 64);
    uint32_t S1s = (uint32_t)__shfl_xor((int)S1, 16, 64);
    t0 = (l & 16) ? S1s : S0;
    t1 = (l & 16) ? S1 : S0s;
#endif
}

// One flash STRIP: 32 q-rows/wave (2 q-subtiles) x 32 keys (wk's half of the
// staged 64-key tile). Exactly the first half of the verified fa7_tile path:
// pf = pA wiring, V strip chunks = fo0/fo1 selected by wk, K rows offset wk*32.
template <bool MASK>
__device__ __forceinline__ void fa12_tile(
    const unsigned short* Ksb, const unsigned short* Vsb,
    const bf16x8 qf[2][2], f32x4 o[2][4], float* l_part,
    int k0, int q_abs0, int quad, int l16, int wk, int fo0, int fo1)
{
    const int fos = wk ? fo1 : fo0;    // strip's logical chunks (4*wk+quad)^sw
    bf16x8 kf[2][2];
    #pragma unroll
    for (int s = 0; s < 2; ++s) {
        const unsigned short* krow = Ksb + (wk * 32 + s * 16 + l16) * 64;
        kf[s][0] = ld_bf8(krow + fo0);
        kf[s][1] = ld_bf8(krow + fo1);
    }

    bf16x8 pf[2];
    #pragma unroll
    for (int qs = 0; qs < 2; ++qs) {
        f32x4 st[2];
        __builtin_amdgcn_s_setprio(1);
        #pragma unroll
        for (int s = 0; s < 2; ++s) {
            f32x4 z = {};
            z = __builtin_amdgcn_mfma_f32_16x16x32_bf16(kf[s][0], qf[qs][0], z, 0, 0, 0);
            st[s] = __builtin_amdgcn_mfma_f32_16x16x32_bf16(kf[s][1], qf[qs][1], z, 0, 0, 0);
        }
        __builtin_amdgcn_s_setprio(0);

        float ts = 0.f;
        #pragma unroll
        for (int s = 0; s < 2; ++s)
            #pragma unroll
            for (int r = 0; r < 4; ++r) {
                float v = st[s][r];
                if (MASK) {
                    int key = k0 + s * 16 + quad * 4 + r;
                    v = (key <= q_abs0 + qs * 16) ? v : NEG_BIG;
                }
                float e = __builtin_amdgcn_exp2f(v);   // exp2(-30000) = 0
                st[s][r] = e;
                ts += e;
            }
        l_part[qs] += ts;

        // pack strip P: W[s][p] = strip keys 16s+4*quad+2p..+1 (col = l16)
        uint32_t W[2][2];
        #pragma unroll
        for (int s = 0; s < 2; ++s) {
            W[s][0] = pk_bf16(st[s][0], st[s][1]);
            W[s][1] = pk_bf16(st[s][2], st[s][3]);
        }
        // redistribute: lane holds strip keys 8*quad..8*quad+7 (B-operand)
        union { uint32_t w[4]; bf16x8 v; } pA;
        quad_xpose_pair(W[0][0], W[1][0], pA.w[0], pA.w[2]);
        quad_xpose_pair(W[0][1], W[1][1], pA.w[1], pA.w[3]);
        pf[qs] = pA.v;
    }

    // V strip: rows = channels (c*16 + l16), cols = this wk's 32 keys
    bf16x8 vf[4];
    #pragma unroll
    for (int c = 0; c < 4; ++c)
        vf[c] = ld_bf8(Vsb + (c * 16 + l16) * 64 + fos);
    __builtin_amdgcn_s_setprio(1);
    #pragma unroll
    for (int qs = 0; qs < 2; ++qs)
        #pragma unroll
        for (int c = 0; c < 4; ++c)
            o[qs][c] = __builtin_amdgcn_mfma_f32_16x16x32_bf16(vf[c], pf[qs], o[qs][c], 0, 0, 0);
    __builtin_amdgcn_s_setprio(0);
}

// Flash v12: flash8's exact sync skeleton (1 barrier/round, dbuf alternation,
// LPT 1024 blocks, cross-wk LDS reduction) with HALF the staged unit: one
// 64-key K/V tile per round, wk waves split it into 32-key strips.
// LDS 32KB -> 5 blocks/CU (all 1024 blocks co-resident).
__global__ __launch_bounds__(256, 4) void flash_attn12(
    const unsigned short* __restrict__ qkv,
    const unsigned short* __restrict__ Vt,
    unsigned short* __restrict__ Y)
{
    __shared__ __attribute__((aligned(16))) unsigned short Ks[2][4096]; // [buf][64 keys x 64 d]
    __shared__ __attribute__((aligned(16))) unsigned short Vs[2][4096]; // [buf][64 ch x 64 keys]

    const int tid  = threadIdx.x;
    const int wave = tid >> 6, lane = tid & 63;
    const int quad = lane >> 4, l16 = lane & 15;
    const int wq = wave >> 1, wk = wave & 1;

    // LPT order: first 512 blocks = qb 63..32 (longest first), then 31..0
    const int bi = blockIdx.x;
    const int h  = bi & 15;
    const int qb = (bi < 512) ? (63 - (bi >> 4)) : (31 - ((bi - 512) >> 4));

    const int q0w    = qb * 64 + wq * 32;
    const int q_abs0 = q0w + l16;              // qs=0 row; qs=1 adds 16
    const int sw  = l16 & 7;
    const int fo0 = (quad ^ sw) * 8;
    const int fo1 = ((quad + 4) ^ sw) * 8;

    // Q fragments (B-operand), prescaled by 0.125*log2(e); 2 q-subtiles
    bf16x8 qf[2][2];
    {
        const float QS = 0.125f * 1.44269504f;
        #pragma unroll
        for (int qs = 0; qs < 2; ++qs) {
            const unsigned short* qp =
                qkv + (size_t)(q0w + qs * 16 + l16) * C3 + h * HD + quad * 8;
            bf16x8 a = ld_bf8(qp), b = ld_bf8(qp + 32);
            #pragma unroll
            for (int i = 0; i < 8; ++i) {
                qf[qs][0][i] = (__bf16)((float)a[i] * QS);
                qf[qs][1][i] = (__bf16)((float)b[i] * QS);
            }
        }
    }

    // Staging roles (independent of compute roles): waves 0,1 -> K halves;
    // waves 2,3 -> V halves. 4 g2l16 calls/wave/round.
    const int tt = wave >> 1, hf = wave & 1;
    const int srow   = lane >> 3;              // 0..7
    const int schunk = (lane & 7) ^ srow;      // XOR swizzle chunk (sw = row&7)
    const unsigned short* gp;
    size_t gstep, rstep;
    unsigned short* lbase;
    if (tt == 0) {
        gp = qkv + (size_t)(hf * 32 + srow) * C3 + C_DIM + h * HD + schunk * 8;
        gstep = (size_t)8 * C3;
        rstep = (size_t)64 * C3;
        lbase = &Ks[0][(hf * 32) * 64];
    } else {
        gp = Vt + (size_t)(h * HD + hf * 32 + srow) * T_SEQ + schunk * 8;
        gstep = (size_t)8 * T_SEQ;
        rstep = (size_t)64;
        lbase = &Vs[0][(hf * 32) * 64];
    }

    auto stage = [&](int b) {
        #pragma unroll
        for (int jj = 0; jj < 4; ++jj)
            async_g2l16(gp + jj * gstep, lbase + b * 4096 + jj * 8 * 64);
    };

    f32x4 o[2][4] = {};
    float l_part[2] = {0.f, 0.f};

    const int nt = qb + 1;
    stage(0);
    gp += rstep;

    for (int t = 0; t < nt; ++t) {
        __syncthreads();
        const int b = t & 1;
        if (t + 1 < nt) {
            stage(1 - b);
            gp += rstep;
        }
        if (t == nt - 1)
            fa12_tile<true>(Ks[b], Vs[b], qf, o, l_part,
                            t * 64 + wk * 32, q_abs0, quad, l16, wk, fo0, fo1);
        else
            fa12_tile<false>(Ks[b], Vs[b], qf, o, l_part,
                             t * 64 + wk * 32, q_abs0, quad, l16, wk, fo0, fo1);
    }

    // Cross-wk reduction through LDS (max-free softmax: partials just add).
    __syncthreads();
    float* red  = (float*)&Ks[0][0];           // 16 KB (exactly Ks)
    float* lred = (float*)&Vs[0][0];           // 1 KB used
    if (wk == 1) {
        #pragma unroll
        for (int qs = 0; qs < 2; ++qs)
            #pragma unroll
            for (int c = 0; c < 4; ++c)
                *(f32x4*)&red[((wq * 8 + qs * 4 + c) * 64 + lane) * 4] = o[qs][c];
        lred[wq * 128 + lane * 2 + 0] = l_part[0];
        lred[wq * 128 + lane * 2 + 1] = l_part[1];
    }
    __syncthreads();
    if (wk == 0) {
        #pragma unroll
        for (int qs = 0; qs < 2; ++qs) {
            #pragma unroll
            for (int c = 0; c < 4; ++c) {
                f32x4 p = *(f32x4*)&red[((wq * 8 + qs * 4 + c) * 64 + lane) * 4];
                o[qs][c] += p;
            }
            l_part[qs] += lred[wq * 128 + lane * 2 + qs];
        }

        #pragma unroll
        for (int qs = 0; qs < 2; ++qs) {
            float l = l_part[qs];
            l += __shfl_xor(l, 16, 64);
            l += __shfl_xor(l, 32, 64);
            float inv_l = 1.f / l;
            #pragma unroll
            for (int c = 0; c < 4; ++c) {
                union { uint32_t w[2]; uint2 q; } t;
                t.w[0] = pk_bf16(o[qs][c][0] * inv_l, o[qs][c][1] * inv_l);
                t.w[1] = pk_bf16(o[qs][c][2] * inv_l, o[qs][c][3] * inv_l);
                *(uint2*)(Y + (size_t)(q_abs0 + qs * 16) * C_DIM + h * HD + c * 16 + quad * 4) = t.q;
            }
        }
    }
}

extern "C" void kernel_launch(void* const* d_in, const int* in_sizes, int n_in,
                              void* d_out, int out_size, void* d_ws, size_t ws_size,
                              hipStream_t stream) {
    const float* x      = (const float*)d_in[0];
    const float* w_attn = (const float*)d_in[1];
    const float* w_proj = (const float*)d_in[2];
    float* out = (float*)d_out;

    unsigned short* qkv = (unsigned short*)d_ws;            // [4096,3072] bf16 (V cols unused)
    unsigned short* xb  = qkv + (size_t)T_SEQ * C3;         // [4096,1024] bf16
    unsigned short* y   = xb;                               // alias after gemm1
    unsigned short* Vt  = (unsigned short*)d_out;           // [1024][4096] bf16
    unsigned short* wab = Vt + (size_t)C_DIM * T_SEQ;       // [3072,1024] bf16

    const size_t need = ((size_t)T_SEQ * C3 + (size_t)T_SEQ * C_DIM +
                         (size_t)C_DIM * C_DIM) * sizeof(unsigned short);
    const bool fuse_wp = ws_size >= need;
    unsigned short* wpb = fuse_wp ? (xb + (size_t)T_SEQ * C_DIM)
                                  : qkv;

    if (fuse_wp) {
        const int n8 = (T_SEQ * C_DIM + C3 * C_DIM + C_DIM * C_DIM) / 8;
        cvt_all<<<n8 / 256, 256, 0, stream>>>(x, w_attn, w_proj, xb, wab, wpb);
    } else {
        const int n8 = (T_SEQ * C_DIM + C3 * C_DIM) / 8;
        cvt_all<<<n8 / 256, 256, 0, stream>>>(x, w_attn, nullptr, xb, wab, nullptr);
    }

    // gemm1 with fused V-transpose epilogue (V blocks write Vt directly)
    gemm_bt<128, unsigned short>
        <<<dim3(C3 / 128, T_SEQ / 128), 256, 0, stream>>>(xb, wab, qkv, Vt, T_SEQ, C3, C_DIM);

    flash_attn12<<<dim3(1024), 256, 0, stream>>>(qkv, Vt, y);

    if (!fuse_wp) {
        cvt_f32_bf16<<<(C_DIM * C_DIM / 8 + 255) / 256, 256, 0, stream>>>(w_proj, wpb, C_DIM * C_DIM);
    }

    gemm_bt<64, float>
        <<<dim3(C_DIM / 128, T_SEQ / 64), 128, 0, stream>>>(y, wpb, out, nullptr, T_SEQ, C_DIM, C_DIM);
}

// Round 13
// 186.102 us; speedup vs baseline: 1.2701x; 1.0208x over previous
//
#include <hip/hip_runtime.h>
#include <hip/hip_bf16.h>
#include <stdint.h>

typedef __bf16 bf16x8 __attribute__((ext_vector_type(8)));
typedef float f32x4 __attribute__((ext_vector_type(4)));

#define T_SEQ 4096
#define C_DIM 1024
#define H_NUM 16
#define HD 64
#define C3 3072
#define NEG_BIG (-30000.0f)

__device__ __forceinline__ unsigned short f2bf(float f) {
    uint32_t u = __builtin_bit_cast(uint32_t, f);
    u += 0x7fffu + ((u >> 16) & 1u);
    return (unsigned short)(u >> 16);
}

__device__ __forceinline__ uint32_t pk_bf16(float a, float b) {
    __hip_bfloat162 h = __float22bfloat162_rn(float2{a, b});
    uint32_t u;
    __builtin_memcpy(&u, &h, sizeof(u));
    return u;
}

__device__ __forceinline__ bf16x8 ld_bf8(const unsigned short* p) {
    return *reinterpret_cast<const bf16x8*>(p);
}

__device__ __forceinline__ void async_g2l16(const unsigned short* g, unsigned short* l) {
    __builtin_amdgcn_global_load_lds(
        (const __attribute__((address_space(1))) void*)g,
        (__attribute__((address_space(3))) void*)l, 16, 0, 0);
}

__device__ __forceinline__ void store_c(unsigned short* C, size_t idx, float v) { C[idx] = f2bf(v); }
__device__ __forceinline__ void store_c(float* C, size_t idx, float v)          { C[idx] = v; }

__device__ __forceinline__ void cvt8(const float* src, unsigned short* dst) {
    float4 f0 = *(const float4*)src;
    float4 f1 = *(const float4*)(src + 4);
    union { uint32_t w[4]; uint4 q; } t;
    t.w[0] = pk_bf16(f0.x, f0.y);
    t.w[1] = pk_bf16(f0.z, f0.w);
    t.w[2] = pk_bf16(f1.x, f1.y);
    t.w[3] = pk_bf16(f1.z, f1.w);
    *(uint4*)dst = t.q;
}

// x, w_attn, (optionally w_proj) fp32 -> bf16 in one launch (concatenated index space)
__global__ void cvt_all(const float* __restrict__ x, const float* __restrict__ wa,
                        const float* __restrict__ wp,
                        unsigned short* __restrict__ xb, unsigned short* __restrict__ wab,
                        unsigned short* __restrict__ wpb) {
    int i = (blockIdx.x * blockDim.x + threadIdx.x) * 8;
    if (i < T_SEQ * C_DIM) { cvt8(x + i, xb + i); return; }
    i -= T_SEQ * C_DIM;
    if (i < C3 * C_DIM) { cvt8(wa + i, wab + i); return; }
    i -= C3 * C_DIM;
    if (wpb != nullptr && i < C_DIM * C_DIM) cvt8(wp + i, wpb + i);
}

__global__ void cvt_f32_bf16(const float* __restrict__ src, unsigned short* __restrict__ dst, int n) {
    int i = (blockIdx.x * blockDim.x + threadIdx.x) * 8;
    if (i >= n) return;
    cvt8(src + i, dst + i);
}

// C = A @ B^T, bf16, m97 async staging. Tile BM x 128, BK=32.
// If VT != nullptr, blocks with n0 >= 2048 (the V columns of qkv) write their
// output TRANSPOSED into VT[1024][4096] instead of C (fuses v_transpose).
template <int BM, typename TC>
__global__ __launch_bounds__(BM * 2, (BM == 128) ? 2 : 3) void gemm_bt(
    const unsigned short* __restrict__ A, const unsigned short* __restrict__ B,
    TC* __restrict__ C, unsigned short* __restrict__ VT, int M, int N, int K)
{
    __shared__ __attribute__((aligned(16))) unsigned short As[BM * 32];
    __shared__ __attribute__((aligned(16))) unsigned short Bs[128 * 32];

    const int tid  = threadIdx.x;
    const int wave = tid >> 6, lane = tid & 63;
    const int quad = lane >> 4, l16 = lane & 15;
    const int wm = (BM == 128) ? (wave >> 1) : 0;
    const int wn = (BM == 128) ? (wave & 1) : wave;
    const int m0 = blockIdx.y * BM, n0 = blockIdx.x * 128;

    const int sr   = lane >> 2;        // 0..15
    const int scol = (lane & 3) * 8;

    f32x4 acc[4][4] = {};

    for (int k0 = 0; k0 < K; k0 += 32) {
        if constexpr (BM == 128) {
            const unsigned short* ga = A + (size_t)(m0 + wave * 32 + sr) * K + k0 + scol;
            const unsigned short* gb = B + (size_t)(n0 + wave * 32 + sr) * K + k0 + scol;
            unsigned short* la = As + (wave * 32) * 32;
            unsigned short* lb = Bs + (wave * 32) * 32;
            async_g2l16(ga, la);
            async_g2l16(ga + (size_t)16 * K, la + 16 * 32);
            async_g2l16(gb, lb);
            async_g2l16(gb + (size_t)16 * K, lb + 16 * 32);
        } else {
            const unsigned short* ga = A + (size_t)(m0 + wave * 32 + sr) * K + k0 + scol;
            unsigned short* la = As + (wave * 32) * 32;
            async_g2l16(ga, la);
            async_g2l16(ga + (size_t)16 * K, la + 16 * 32);
            const unsigned short* gb = B + (size_t)(n0 + wave * 64 + sr) * K + k0 + scol;
            unsigned short* lb = Bs + (wave * 64) * 32;
            async_g2l16(gb, lb);
            async_g2l16(gb + (size_t)16 * K, lb + 16 * 32);
            async_g2l16(gb + (size_t)32 * K, lb + 32 * 32);
            async_g2l16(gb + (size_t)48 * K, lb + 48 * 32);
        }
        __syncthreads();

        bf16x8 af[4], bf[4];
        #pragma unroll
        for (int i = 0; i < 4; ++i) {
            af[i] = ld_bf8(As + (wm * 64 + i * 16 + l16) * 32 + quad * 8);
            bf[i] = ld_bf8(Bs + (wn * 64 + i * 16 + l16) * 32 + quad * 8);
        }
        #pragma unroll
        for (int mt = 0; mt < 4; ++mt)
            #pragma unroll
            for (int nt = 0; nt < 4; ++nt)
                acc[mt][nt] = __builtin_amdgcn_mfma_f32_16x16x32_bf16(
                    af[mt], bf[nt], acc[mt][nt], 0, 0, 0);
        __syncthreads();
    }

    if (VT != nullptr && n0 >= 2 * C_DIM) {
        #pragma unroll
        for (int mt = 0; mt < 4; ++mt)
            #pragma unroll
            for (int nt = 0; nt < 4; ++nt) {
                const int ch = n0 - 2 * C_DIM + wn * 64 + nt * 16 + l16;
                const int t0 = m0 + wm * 64 + mt * 16 + quad * 4;
                union { unsigned short u[4]; uint2 q; } pk;
                #pragma unroll
                for (int r = 0; r < 4; ++r) pk.u[r] = f2bf(acc[mt][nt][r]);
                *(uint2*)(VT + (size_t)ch * T_SEQ + t0) = pk.q;
            }
    } else {
        #pragma unroll
        for (int mt = 0; mt < 4; ++mt)
            #pragma unroll
            for (int nt = 0; nt < 4; ++nt)
                #pragma unroll
                for (int r = 0; r < 4; ++r) {
                    int row = m0 + wm * 64 + mt * 16 + quad * 4 + r;
                    int col = n0 + wn * 64 + nt * 16 + l16;
                    store_c(C, (size_t)row * N + col, acc[mt][nt][r]);
                }
    }
}

// Register-level quad transpose for the P fragment (replaces the LDS round-trip).
#if __has_builtin(__builtin_amdgcn_permlane32_swap) && __has_builtin(__builtin_amdgcn_permlane16_swap)
#define HAVE_PERMLANE_SWAP 1
#else
#define HAVE_PERMLANE_SWAP 0
#endif

__device__ __forceinline__ void quad_xpose_pair(uint32_t X, uint32_t Y,
                                                uint32_t& t0, uint32_t& t1) {
#if HAVE_PERMLANE_SWAP
    auto S = __builtin_amdgcn_permlane32_swap((int)X, (int)Y, false, false);
    auto T = __builtin_amdgcn_permlane16_swap((int)S[0], (int)S[1], false, false);
    t0 = (uint32_t)T[0];
    t1 = (uint32_t)T[1];
#else
    const unsigned l = threadIdx.x & 63;
    uint32_t Ys = (uint32_t)__shfl_xor((int)Y, 32, 64);
    uint32_t Xs = (uint32_t)__shfl_xor((int)X, 32, 64);
    uint32_t S0 = (l < 32) ? X : Ys;   // {A.low32, B.low32}
    uint32_t S1 = (l < 32) ? Xs : Y;   // {A.high32, B.high32}
    uint32_t S0s = (uint32_t)__shfl_xor((int)S0, 16, 64);
    uint32_t S1s = (uint32_t)__shfl_xor((int)S1, 16, 64);
    t0 = (l & 16) ? S1s : S0;
    t1 = (l & 16) ? S1 : S0s;
#endif
}

// One flash STRIP: 32 q-rows/wave (2 q-subtiles) x 32 keys (wk's half of the
// staged 64-key tile).
template <bool MASK>
__device__ __forceinline__ void fa12_tile(
    const unsigned short* Ksb, const unsigned short* Vsb,
    const bf16x8 qf[2][2], f32x4 o[2][4], float* l_part,
    int k0, int q_abs0, int quad, int l16, int wk, int fo0, int fo1)
{
    const int fos = wk ? fo1 : fo0;    // strip's logical chunks (4*wk+quad)^sw
    bf16x8 kf[2][2];
    #pragma unroll
    for (int s = 0; s < 2; ++s) {
        const unsigned short* krow = Ksb + (wk * 32 + s * 16 + l16) * 64;
        kf[s][0] = ld_bf8(krow + fo0);
        kf[s][1] = ld_bf8(krow + fo1);
    }

    bf16x8 pf[2];
    #pragma unroll
    for (int qs = 0; qs < 2; ++qs) {
        f32x4 st[2];
        __builtin_amdgcn_s_setprio(1);
        #pragma unroll
        for (int s = 0; s < 2; ++s) {
            f32x4 z = {};
            z = __builtin_amdgcn_mfma_f32_16x16x32_bf16(kf[s][0], qf[qs][0], z, 0, 0, 0);
            st[s] = __builtin_amdgcn_mfma_f32_16x16x32_bf16(kf[s][1], qf[qs][1], z, 0, 0, 0);
        }
        __builtin_amdgcn_s_setprio(0);

        float ts = 0.f;
        #pragma unroll
        for (int s = 0; s < 2; ++s)
            #pragma unroll
            for (int r = 0; r < 4; ++r) {
                float v = st[s][r];
                if (MASK) {
                    int key = k0 + s * 16 + quad * 4 + r;
                    v = (key <= q_abs0 + qs * 16) ? v : NEG_BIG;
                }
                float e = __builtin_amdgcn_exp2f(v);   // exp2(-30000) = 0
                st[s][r] = e;
                ts += e;
            }
        l_part[qs] += ts;

        // pack strip P: W[s][p] = strip keys 16s+4*quad+2p..+1 (col = l16)
        uint32_t W[2][2];
        #pragma unroll
        for (int s = 0; s < 2; ++s) {
            W[s][0] = pk_bf16(st[s][0], st[s][1]);
            W[s][1] = pk_bf16(st[s][2], st[s][3]);
        }
        // redistribute: lane holds strip keys 8*quad..8*quad+7 (B-operand)
        union { uint32_t w[4]; bf16x8 v; } pA;
        quad_xpose_pair(W[0][0], W[1][0], pA.w[0], pA.w[2]);
        quad_xpose_pair(W[0][1], W[1][1], pA.w[1], pA.w[3]);
        pf[qs] = pA.v;
    }

    // V strip: rows = channels (c*16 + l16), cols = this wk's 32 keys
    bf16x8 vf[4];
    #pragma unroll
    for (int c = 0; c < 4; ++c)
        vf[c] = ld_bf8(Vsb + (c * 16 + l16) * 64 + fos);
    __builtin_amdgcn_s_setprio(1);
    #pragma unroll
    for (int qs = 0; qs < 2; ++qs)
        #pragma unroll
        for (int c = 0; c < 4; ++c)
            o[qs][c] = __builtin_amdgcn_mfma_f32_16x16x32_bf16(vf[c], pf[qs], o[qs][c], 0, 0, 0);
    __builtin_amdgcn_s_setprio(0);
}

// Flash v12 (R10-proven): flash8's sync skeleton (1 barrier/round, dbuf
// alternation, LPT 1024 blocks, cross-wk LDS reduction) with HALF the staged
// unit: one 64-key K/V tile per round, wk waves split it into 32-key strips.
// LDS 32KB -> 5 blocks/CU (all 1024 blocks co-resident).
__global__ __launch_bounds__(256, 4) void flash_attn12(
    const unsigned short* __restrict__ qkv,
    const unsigned short* __restrict__ Vt,
    unsigned short* __restrict__ Y)
{
    __shared__ __attribute__((aligned(16))) unsigned short Ks[2][4096]; // [buf][64 keys x 64 d]
    __shared__ __attribute__((aligned(16))) unsigned short Vs[2][4096]; // [buf][64 ch x 64 keys]

    const int tid  = threadIdx.x;
    const int wave = tid >> 6, lane = tid & 63;
    const int quad = lane >> 4, l16 = lane & 15;
    const int wq = wave >> 1, wk = wave & 1;

    // LPT order: first 512 blocks = qb 63..32 (longest first), then 31..0
    const int bi = blockIdx.x;
    const int h  = bi & 15;
    const int qb = (bi < 512) ? (63 - (bi >> 4)) : (31 - ((bi - 512) >> 4));

    const int q0w    = qb * 64 + wq * 32;
    const int q_abs0 = q0w + l16;              // qs=0 row; qs=1 adds 16
    const int sw  = l16 & 7;
    const int fo0 = (quad ^ sw) * 8;
    const int fo1 = ((quad + 4) ^ sw) * 8;

    // Q fragments (B-operand), prescaled by 0.125*log2(e); 2 q-subtiles
    bf16x8 qf[2][2];
    {
        const float QS = 0.125f * 1.44269504f;
        #pragma unroll
        for (int qs = 0; qs < 2; ++qs) {
            const unsigned short* qp =
                qkv + (size_t)(q0w + qs * 16 + l16) * C3 + h * HD + quad * 8;
            bf16x8 a = ld_bf8(qp), b = ld_bf8(qp + 32);
            #pragma unroll
            for (int i = 0; i < 8; ++i) {
                qf[qs][0][i] = (__bf16)((float)a[i] * QS);
                qf[qs][1][i] = (__bf16)((float)b[i] * QS);
            }
        }
    }

    // Staging roles (independent of compute roles): waves 0,1 -> K halves;
    // waves 2,3 -> V halves. 4 g2l16 calls/wave/round.
    const int tt = wave >> 1, hf = wave & 1;
    const int srow   = lane >> 3;              // 0..7
    const int schunk = (lane & 7) ^ srow;      // XOR swizzle chunk (sw = row&7)
    const unsigned short* gp;
    size_t gstep, rstep;
    unsigned short* lbase;
    if (tt == 0) {
        gp = qkv + (size_t)(hf * 32 + srow) * C3 + C_DIM + h * HD + schunk * 8;
        gstep = (size_t)8 * C3;
        rstep = (size_t)64 * C3;
        lbase = &Ks[0][(hf * 32) * 64];
    } else {
        gp = Vt + (size_t)(h * HD + hf * 32 + srow) * T_SEQ + schunk * 8;
        gstep = (size_t)8 * T_SEQ;
        rstep = (size_t)64;
        lbase = &Vs[0][(hf * 32) * 64];
    }

    auto stage = [&](int b) {
        #pragma unroll
        for (int jj = 0; jj < 4; ++jj)
            async_g2l16(gp + jj * gstep, lbase + b * 4096 + jj * 8 * 64);
    };

    f32x4 o[2][4] = {};
    float l_part[2] = {0.f, 0.f};

    const int nt = qb + 1;
    stage(0);
    gp += rstep;

    for (int t = 0; t < nt; ++t) {
        __syncthreads();
        const int b = t & 1;
        if (t + 1 < nt) {
            stage(1 - b);
            gp += rstep;
        }
        if (t == nt - 1)
            fa12_tile<true>(Ks[b], Vs[b], qf, o, l_part,
                            t * 64 + wk * 32, q_abs0, quad, l16, wk, fo0, fo1);
        else
            fa12_tile<false>(Ks[b], Vs[b], qf, o, l_part,
                             t * 64 + wk * 32, q_abs0, quad, l16, wk, fo0, fo1);
    }

    // Cross-wk reduction through LDS (max-free softmax: partials just add).
    __syncthreads();
    float* red  = (float*)&Ks[0][0];           // 16 KB (exactly Ks)
    float* lred = (float*)&Vs[0][0];           // 1 KB used
    if (wk == 1) {
        #pragma unroll
        for (int qs = 0; qs < 2; ++qs)
            #pragma unroll
            for (int c = 0; c < 4; ++c)
                *(f32x4*)&red[((wq * 8 + qs * 4 + c) * 64 + lane) * 4] = o[qs][c];
        lred[wq * 128 + lane * 2 + 0] = l_part[0];
        lred[wq * 128 + lane * 2 + 1] = l_part[1];
    }
    __syncthreads();
    if (wk == 0) {
        #pragma unroll
        for (int qs = 0; qs < 2; ++qs) {
            #pragma unroll
            for (int c = 0; c < 4; ++c) {
                f32x4 p = *(f32x4*)&red[((wq * 8 + qs * 4 + c) * 64 + lane) * 4];
                o[qs][c] += p;
            }
            l_part[qs] += lred[wq * 128 + lane * 2 + qs];
        }

        #pragma unroll
        for (int qs = 0; qs < 2; ++qs) {
            float l = l_part[qs];
            l += __shfl_xor(l, 16, 64);
            l += __shfl_xor(l, 32, 64);
            float inv_l = 1.f / l;
            #pragma unroll
            for (int c = 0; c < 4; ++c) {
                union { uint32_t w[2]; uint2 q; } t;
                t.w[0] = pk_bf16(o[qs][c][0] * inv_l, o[qs][c][1] * inv_l);
                t.w[1] = pk_bf16(o[qs][c][2] * inv_l, o[qs][c][3] * inv_l);
                *(uint2*)(Y + (size_t)(q_abs0 + qs * 16) * C_DIM + h * HD + c * 16 + quad * 4) = t.q;
            }
        }
    }
}

extern "C" void kernel_launch(void* const* d_in, const int* in_sizes, int n_in,
                              void* d_out, int out_size, void* d_ws, size_t ws_size,
                              hipStream_t stream) {
    const float* x      = (const float*)d_in[0];
    const float* w_attn = (const float*)d_in[1];
    const float* w_proj = (const float*)d_in[2];
    float* out = (float*)d_out;

    unsigned short* qkv = (unsigned short*)d_ws;            // [4096,3072] bf16 (V cols unused)
    unsigned short* xb  = qkv + (size_t)T_SEQ * C3;         // [4096,1024] bf16
    unsigned short* y   = xb;                               // alias after gemm1
    unsigned short* Vt  = (unsigned short*)d_out;           // [1024][4096] bf16
    unsigned short* wab = Vt + (size_t)C_DIM * T_SEQ;       // [3072,1024] bf16

    const size_t need = ((size_t)T_SEQ * C3 + (size_t)T_SEQ * C_DIM +
                         (size_t)C_DIM * C_DIM) * sizeof(unsigned short);
    const bool fuse_wp = ws_size >= need;
    unsigned short* wpb = fuse_wp ? (xb + (size_t)T_SEQ * C_DIM)
                                  : qkv;

    if (fuse_wp) {
        const int n8 = (T_SEQ * C_DIM + C3 * C_DIM + C_DIM * C_DIM) / 8;
        cvt_all<<<n8 / 256, 256, 0, stream>>>(x, w_attn, w_proj, xb, wab, wpb);
    } else {
        const int n8 = (T_SEQ * C_DIM + C3 * C_DIM) / 8;
        cvt_all<<<n8 / 256, 256, 0, stream>>>(x, w_attn, nullptr, xb, wab, nullptr);
    }

    // gemm1 with fused V-transpose epilogue (V blocks write Vt directly)
    gemm_bt<128, unsigned short>
        <<<dim3(C3 / 128, T_SEQ / 128), 256, 0, stream>>>(xb, wab, qkv, Vt, T_SEQ, C3, C_DIM);

    flash_attn12<<<dim3(1024), 256, 0, stream>>>(qkv, Vt, y);

    if (!fuse_wp) {
        cvt_f32_bf16<<<(C_DIM * C_DIM / 8 + 255) / 256, 256, 0, stream>>>(w_proj, wpb, C_DIM * C_DIM);
    }

    gemm_bt<64, float>
        <<<dim3(C_DIM / 128, T_SEQ / 64), 128, 0, stream>>>(y, wpb, out, nullptr, T_SEQ, C_DIM, C_DIM);
}